// Round 1
// baseline (304.850 us; speedup 1.0000x reference)
//
#include <hip/hip_runtime.h>

#define NN 50000
#define EE 800000
#define HC 128
#define GG 64

__device__ __forceinline__ float lrelu(float x) { return x >= 0.0f ? x : 0.2f * x; }

// sum across each 32-lane half of the wave (masks <32 never cross the bit-5 boundary)
__device__ __forceinline__ float gsum32(float t) {
  t += __shfl_xor(t, 1);
  t += __shfl_xor(t, 2);
  t += __shfl_xor(t, 4);
  t += __shfl_xor(t, 8);
  t += __shfl_xor(t, 16);
  return t;
}

// ---------------- GEMM: xl = x@Wl, xr = x@Wr (fp32, vector ALU) ----------------
// block: 256 thr, tile 64 rows x 128 cols, K-chunks of 32. grid.y selects Wl/Wr.
__global__ __launch_bounds__(256) void gemm_xw(
    const float* __restrict__ x, const float* __restrict__ Wl,
    const float* __restrict__ Wr, float* __restrict__ xl, float* __restrict__ xr)
{
  const float* __restrict__ W = blockIdx.y ? Wr : Wl;
  float* __restrict__ out = blockIdx.y ? xr : xl;
  __shared__ __align__(16) float As[32][68];   // [k][row], pad 68 keeps 16B align
  __shared__ __align__(16) float Ws[32][128];  // [k][col]
  const int t = threadIdx.x;
  const int tx = t & 15, ty = t >> 4;
  const int row0 = blockIdx.x * 64;
  float acc[4][8];
#pragma unroll
  for (int i = 0; i < 4; ++i)
#pragma unroll
    for (int j = 0; j < 8; ++j) acc[i][j] = 0.f;

  const int lr = t >> 2;        // local row 0..63
  const int kq = (t & 3) * 8;   // k offset 0,8,16,24
  int arow = row0 + lr; if (arow >= NN) arow = NN - 1;   // clamp tail

  for (int k0 = 0; k0 < 128; k0 += 32) {
    float4 a0 = *(const float4*)(x + (size_t)arow * 128 + k0 + kq);
    float4 a1 = *(const float4*)(x + (size_t)arow * 128 + k0 + kq + 4);
    float4 wv0 = *(const float4*)(W + (k0 + ((t      ) >> 5)) * 128 + ((t      ) & 31) * 4);
    float4 wv1 = *(const float4*)(W + (k0 + ((t + 256) >> 5)) * 128 + ((t + 256) & 31) * 4);
    float4 wv2 = *(const float4*)(W + (k0 + ((t + 512) >> 5)) * 128 + ((t + 512) & 31) * 4);
    float4 wv3 = *(const float4*)(W + (k0 + ((t + 768) >> 5)) * 128 + ((t + 768) & 31) * 4);
    __syncthreads();
    As[kq + 0][lr] = a0.x; As[kq + 1][lr] = a0.y; As[kq + 2][lr] = a0.z; As[kq + 3][lr] = a0.w;
    As[kq + 4][lr] = a1.x; As[kq + 5][lr] = a1.y; As[kq + 6][lr] = a1.z; As[kq + 7][lr] = a1.w;
    *(float4*)&Ws[(t      ) >> 5][((t      ) & 31) * 4] = wv0;
    *(float4*)&Ws[(t + 256) >> 5][((t + 256) & 31) * 4] = wv1;
    *(float4*)&Ws[(t + 512) >> 5][((t + 512) & 31) * 4] = wv2;
    *(float4*)&Ws[(t + 768) >> 5][((t + 768) & 31) * 4] = wv3;
    __syncthreads();
#pragma unroll
    for (int kk = 0; kk < 32; ++kk) {
      float4 av = *(const float4*)&As[kk][ty * 4];
      float4 w0 = *(const float4*)&Ws[kk][tx * 4];
      float4 w1 = *(const float4*)&Ws[kk][64 + tx * 4];
      float a4[4] = {av.x, av.y, av.z, av.w};
      float wv[8] = {w0.x, w0.y, w0.z, w0.w, w1.x, w1.y, w1.z, w1.w};
#pragma unroll
      for (int i = 0; i < 4; ++i)
#pragma unroll
        for (int j = 0; j < 8; ++j) acc[i][j] = fmaf(a4[i], wv[j], acc[i][j]);
    }
  }
#pragma unroll
  for (int i = 0; i < 4; ++i) {
    int row = row0 + ty * 4 + i;
    if (row < NN) {
      float4 c0 = {acc[i][0], acc[i][1], acc[i][2], acc[i][3]};
      float4 c1 = {acc[i][4], acc[i][5], acc[i][6], acc[i][7]};
      *(float4*)(out + (size_t)row * 128 + tx * 4) = c0;
      *(float4*)(out + (size_t)row * 128 + 64 + tx * 4) = c1;
    }
  }
}

// ---------------- CSR build ----------------
__global__ __launch_bounds__(256) void hist_deg(const int* __restrict__ ei, int* __restrict__ deg) {
  int e = blockIdx.x * 256 + threadIdx.x;
  if (e < EE) atomicAdd(&deg[ei[EE + e]], 1);
}

__global__ __launch_bounds__(256) void scan1(const int* __restrict__ deg, int* __restrict__ rs,
                                             int* __restrict__ bsum) {
  __shared__ int tmp[256];
  int t = threadIdx.x;
  int base = blockIdx.x * 1024 + t * 4;
  int v0 = base + 0 < NN ? deg[base + 0] : 0;
  int v1 = base + 1 < NN ? deg[base + 1] : 0;
  int v2 = base + 2 < NN ? deg[base + 2] : 0;
  int v3 = base + 3 < NN ? deg[base + 3] : 0;
  int local = v0 + v1 + v2 + v3;
  tmp[t] = local;
  __syncthreads();
  for (int off = 1; off < 256; off <<= 1) {
    int xv = (t >= off) ? tmp[t - off] : 0;
    __syncthreads();
    tmp[t] += xv;
    __syncthreads();
  }
  int excl = tmp[t] - local;
  if (base + 0 < NN) rs[base + 0] = excl; excl += v0;
  if (base + 1 < NN) rs[base + 1] = excl; excl += v1;
  if (base + 2 < NN) rs[base + 2] = excl; excl += v2;
  if (base + 3 < NN) rs[base + 3] = excl;
  if (t == 255) bsum[blockIdx.x] = tmp[255];
}

__global__ void scan2(int* __restrict__ bsum) {
  __shared__ int tmp[64];
  int t = threadIdx.x;
  const int NB = (NN + 1023) / 1024;  // 49
  int v = t < NB ? bsum[t] : 0;
  tmp[t] = v;
  __syncthreads();
  for (int off = 1; off < 64; off <<= 1) {
    int xv = (t >= off) ? tmp[t - off] : 0;
    __syncthreads();
    tmp[t] += xv;
    __syncthreads();
  }
  if (t < NB) bsum[t] = tmp[t] - v;
}

__global__ __launch_bounds__(256) void scan3(int* __restrict__ rs, int* __restrict__ cursor,
                                             const int* __restrict__ bsum) {
  int i = blockIdx.x * 256 + threadIdx.x;
  if (i < NN) {
    int v = rs[i] + bsum[i >> 10];
    rs[i] = v;
    cursor[i] = v;
  }
  if (i == 0) rs[NN] = EE;
}

__global__ __launch_bounds__(256) void scatter_edges(const int* __restrict__ ei,
                                                     int* __restrict__ cursor,
                                                     int* __restrict__ csr) {
  int e = blockIdx.x * 256 + threadIdx.x;
  if (e < EE) {
    int d = ei[EE + e];
    int pos = atomicAdd(&cursor[d], 1);
    csr[pos] = ei[e];
  }
}

// ---------------- main aggregation: one wave per node, online softmax ----------------
__global__ __launch_bounds__(256) void gat_agg(
    const float* __restrict__ xl, const float* __restrict__ xr,
    const int* __restrict__ rs, const int* __restrict__ csr,
    const float* __restrict__ att, const float* __restrict__ bias,
    float* __restrict__ outn)
{
  int wid = threadIdx.x >> 6, lane = threadIdx.x & 63;
  int n = blockIdx.x * 4 + wid;
  if (n >= NN) return;
  int c0 = lane, c1 = lane + 64;  // lane holds head (lane>>5) ch (lane&31) and head 2+(lane>>5)
  float att0 = att[c0], att1 = att[c1];
  float xr0 = xr[(size_t)n * HC + c0], xr1 = xr[(size_t)n * HC + c1];
  // self loop first (reference appends one self-loop per node)
  float u0 = xl[(size_t)n * HC + c0], u1 = xl[(size_t)n * HC + c1];
  float m0 = gsum32(lrelu(u0 + xr0) * att0);
  float m1 = gsum32(lrelu(u1 + xr1) * att1);
  float s0 = 1.f, s1 = 1.f, a0 = u0, a1 = u1;

  int jbeg = rs[n], jend = rs[n + 1];
  for (int j0 = jbeg; j0 < jend; j0 += 64) {
    int cnt = jend - j0; if (cnt > 64) cnt = 64;
    int sj = (lane < cnt) ? csr[j0 + lane] : 0;
    for (int e = 0; e < cnt; ++e) {
      int src = __shfl(sj, e);
      float v0 = xl[(size_t)src * HC + c0], v1 = xl[(size_t)src * HC + c1];
      float t0 = gsum32(lrelu(v0 + xr0) * att0);
      float t1 = gsum32(lrelu(v1 + xr1) * att1);
      float mn0 = fmaxf(m0, t0), mn1 = fmaxf(m1, t1);
      float sc0 = __expf(m0 - mn0), sc1 = __expf(m1 - mn1);
      float p0 = __expf(t0 - mn0), p1 = __expf(t1 - mn1);
      s0 = s0 * sc0 + p0; a0 = a0 * sc0 + p0 * v0; m0 = mn0;
      s1 = s1 * sc1 + p1; a1 = a1 * sc1 + p1 * v1; m1 = mn1;
    }
  }
  outn[(size_t)n * HC + c0] = fmaxf(a0 / s0 + bias[c0], 0.f);
  outn[(size_t)n * HC + c1] = fmaxf(a1 / s1 + bias[c1], 0.f);
}

// ---------------- pooling (batch_ids sorted -> run-length max, few atomics) ----------------
__global__ __launch_bounds__(128) void pool_max(const float* __restrict__ outn,
                                                const int* __restrict__ batch,
                                                unsigned int* __restrict__ pooled) {
  int c = threadIdx.x;
  int n0 = blockIdx.x * 128;
  int nend = n0 + 128; if (nend > NN) nend = NN;
  int curg = batch[n0];
  float mx = 0.f;  // relu outputs are >= 0
  for (int n = n0; n < nend; ++n) {
    int g = batch[n];
    if (g != curg) {
      atomicMax(&pooled[curg * HC + c], __float_as_uint(mx));  // nonneg: uint order == float order
      mx = 0.f; curg = g;
    }
    mx = fmaxf(mx, outn[(size_t)n * HC + c]);
  }
  atomicMax(&pooled[curg * HC + c], __float_as_uint(mx));
}

// ---------------- MLP head ----------------
__global__ __launch_bounds__(128) void mlp_out(const unsigned int* __restrict__ pooled,
                                               const float* __restrict__ W,
                                               const float* __restrict__ b,
                                               float* __restrict__ out) {
  __shared__ float p[128];
  int g = blockIdx.x, j = threadIdx.x;
  p[j] = __uint_as_float(pooled[g * HC + j]);
  __syncthreads();
  float acc = b[j];
#pragma unroll 8
  for (int k = 0; k < 128; ++k) acc = fmaf(p[k], W[k * 128 + j], acc);
  out[g * HC + j] = fmaxf(acc, 0.f);
}

extern "C" void kernel_launch(void* const* d_in, const int* in_sizes, int n_in,
                              void* d_out, int out_size, void* d_ws, size_t ws_size,
                              hipStream_t stream) {
  const float* x    = (const float*)d_in[0];
  const int*   ei   = (const int*)d_in[1];   // [2,E]: [0..E) = src, [E..2E) = dst
  const int*   batch= (const int*)d_in[2];
  const float* Wl   = (const float*)d_in[4];
  const float* Wr   = (const float*)d_in[5];
  const float* att  = (const float*)d_in[6];
  const float* bias = (const float*)d_in[7];
  const float* Wm   = (const float*)d_in[8];
  const float* bm   = (const float*)d_in[9];

  char* ws = (char*)d_ws;
  size_t off = 0;
  auto alloc = [&](size_t bytes) { void* p = ws + off; off += (bytes + 255) & ~size_t(255); return p; };
  float* xl      = (float*)alloc((size_t)NN * HC * 4);
  float* xr      = (float*)alloc((size_t)NN * HC * 4);
  float* outn    = (float*)alloc((size_t)NN * HC * 4);
  int*   deg     = (int*)alloc((size_t)NN * 4);
  int*   rs      = (int*)alloc((size_t)(NN + 1) * 4);
  int*   cursor  = (int*)alloc((size_t)NN * 4);
  int*   bsum    = (int*)alloc(64 * 4);
  int*   csr     = (int*)alloc((size_t)EE * 4);
  unsigned int* pooled = (unsigned int*)alloc((size_t)GG * HC * 4);

  hipMemsetAsync(deg, 0, (size_t)NN * 4, stream);
  hipMemsetAsync(pooled, 0, (size_t)GG * HC * 4, stream);

  gemm_xw<<<dim3((NN + 63) / 64, 2), 256, 0, stream>>>(x, Wl, Wr, xl, xr);
  hist_deg<<<(EE + 255) / 256, 256, 0, stream>>>(ei, deg);
  scan1<<<(NN + 1023) / 1024, 256, 0, stream>>>(deg, rs, bsum);
  scan2<<<1, 64, 0, stream>>>(bsum);
  scan3<<<(NN + 255) / 256, 256, 0, stream>>>(rs, cursor, bsum);
  scatter_edges<<<(EE + 255) / 256, 256, 0, stream>>>(ei, cursor, csr);
  gat_agg<<<NN / 4, 256, 0, stream>>>(xl, xr, rs, csr, att, bias, outn);
  pool_max<<<(NN + 127) / 128, 128, 0, stream>>>(outn, batch, pooled);
  mlp_out<<<GG, 128, 0, stream>>>(pooled, Wm, bm, (float*)d_out);
}